// Round 21
// baseline (331.229 us; speedup 1.0000x reference)
//
#include <hip/hip_runtime.h>
#include <hip/hip_bf16.h>
#include <stdint.h>

// ---------------------------------------------------------------------------
// MultiheadAttention (B=2,S=2048,E=2048,H=16,D=128), softcap=50, alpha=1
// Inputs FP32, output FP32, dict-order labels (proven r8-r20).
// Round 21: inside gemm8_qkv's phase, software-pipeline the LDS reads
// (bf+af[0..1] up front, af[m+2] prefetched under row-m's 4 MFMA) so the
// DS pipe overlaps the MFMA floor instead of serializing with it (r20
// accounting: phase 2400 cyc = 1242 MFMA + 768 DS + overhead, lockstep).
// Ring schedule, swizzle (0 conflicts), attn, gemm_out, cvt unchanged.
// ---------------------------------------------------------------------------

typedef __attribute__((ext_vector_type(8))) short s16x8;   // 8 bf16
typedef __attribute__((ext_vector_type(4))) float f32x4;

typedef const __attribute__((address_space(1))) char* gcptr;
typedef __attribute__((address_space(3))) char* lcptr;

#define MFMA_BF16(a, b, c) __builtin_amdgcn_mfma_f32_16x16x32_bf16((a), (b), (c), 0, 0, 0)

__device__ __forceinline__ short f2bf(float f) {          // fp32 -> bf16 RNE
  union { float f; unsigned u; } x; x.f = f;
  unsigned r = (x.u + 0x7fffu + ((x.u >> 16) & 1u)) >> 16;
  return (short)r;
}

__device__ __forceinline__ void gload16(const void* g, void* lds) {
  __builtin_amdgcn_global_load_lds((gcptr)g, (lcptr)lds, 16, 0, 0);
}

constexpr int GK = 2048;
constexpr int SL = 2048, EMB = 2048, HD = 128;

// ---------------------------------------------------------------------------
// Merged fp32 -> bf16 conversion (unchanged).
// ---------------------------------------------------------------------------
__global__ void cvt_all(const float* __restrict__ q, const float* __restrict__ k,
                        const float* __restrict__ v, const float* __restrict__ wq,
                        const float* __restrict__ wk, const float* __restrict__ wv,
                        const float* __restrict__ wo, short* __restrict__ dst) {
  const int N8A = 1 << 20, N8W = 1 << 19;
  const int total = 3 * N8A + 4 * N8W;
  int i = blockIdx.x * blockDim.x + threadIdx.x;
  int stride = gridDim.x * blockDim.x;
  for (; i < total; i += stride) {
    const float* src;
    size_t loc;
    if (i < 3 * N8A) {
      int sel = i >> 20;
      loc = (size_t)(i & (N8A - 1));
      src = sel == 0 ? q : (sel == 1 ? k : v);
    } else {
      int w = i - 3 * N8A;
      int sel = w >> 19;
      loc = (size_t)(w & (N8W - 1));
      src = sel == 0 ? wq : (sel == 1 ? wk : (sel == 2 ? wv : wo));
    }
    f32x4 a = *reinterpret_cast<const f32x4*>(src + loc * 8);
    f32x4 b = *reinterpret_cast<const f32x4*>(src + loc * 8 + 4);
    s16x8 w8;
#pragma unroll
    for (int j = 0; j < 4; ++j) { w8[j] = f2bf(a[j]); w8[4 + j] = f2bf(b[j]); }
    *reinterpret_cast<s16x8*>(dst + (size_t)i * 8) = w8;
  }
}

// ---------------------------------------------------------------------------
// 256^2 pipelined QKV GEMM (r20 + intra-phase read/MFMA interleave).
// ---------------------------------------------------------------------------
__global__ __launch_bounds__(512, 1)
void gemm8_qkv(const short* __restrict__ a0, const short* __restrict__ a1,
               const short* __restrict__ w0, const short* __restrict__ w1,
               const short* __restrict__ w2, const short* __restrict__ a2,
               short* __restrict__ o0, short* __restrict__ o1,
               short* __restrict__ o2) {
  __shared__ __align__(16) short Lds[4 * 16384];   // 128 KiB

  const int z = blockIdx.z;
  const short* A = z == 0 ? a0 : (z == 1 ? a1 : w2);
  const short* B = z == 0 ? w0 : (z == 1 ? w1 : a2);
  short* C = z == 0 ? o0 : (z == 1 ? o1 : o2);
  const int gn = z == 2 ? 4096 : 2048;

  const int j = blockIdx.x + (blockIdx.y << 3);
  int bm, bn;
  if (z == 2) { bm = j & 7; bn = j >> 3; }
  else        { bm = ((j & 7) << 1) + ((j >> 3) & 1); bn = j >> 4; }

  const int tid = threadIdx.x;
  const int lane = tid & 63;
  const int wid = tid >> 6;
  const int wm = wid >> 2, wn = wid & 3;
  const int g = lane >> 4, r = lane & 15;
  const int pg = g ^ ((r >> 1) & 3);

  const size_t Abase = (size_t)bm * 256 * GK;
  const size_t Bbase = (size_t)bn * 256 * GK;

  const f32x4 fz = {0.f, 0.f, 0.f, 0.f};
  f32x4 acc[8][4];
#pragma unroll
  for (int m = 0; m < 8; ++m)
#pragma unroll
    for (int n = 0; n < 4; ++n) acc[m][n] = fz;

  auto issueHalf = [&](int n) {
    const int reg = (n & 3) * 16384;
    const int k0 = (n << 5) & (GK - 1);
#pragma unroll
    for (int i = 0; i < 2; ++i) {
      int c = tid + i * 512;
      int row = c >> 2;
      int lg = (c & 3) ^ ((c >> 3) & 3);
      gload16(A + Abase + (size_t)row * GK + k0 + lg * 8, Lds + reg + c * 8);
    }
#pragma unroll
    for (int i = 0; i < 2; ++i) {
      int c = tid + i * 512;
      int row = c >> 2;
      int lg = (c & 3) ^ ((c >> 3) & 3);
      gload16(B + Bbase + (size_t)row * GK + k0 + lg * 8, Lds + reg + 8192 + c * 8);
    }
  };

  issueHalf(0);
  issueHalf(1);
  issueHalf(2);

  for (int t2 = 0; t2 < 16; ++t2) {
#pragma unroll
    for (int p = 0; p < 4; ++p) {
      const int n = t2 * 4 + p;
      issueHalf(n + 3);
      asm volatile("s_waitcnt vmcnt(12)" ::: "memory");
      asm volatile("s_barrier" ::: "memory");

      const int areg = p * 16384;
      const short* Abuf = Lds + areg;
      const short* Bbuf = Lds + areg + 8192;

      // ---- interleaved reads/MFMA: bf + af[0..1] first, af[m+2] under
      //      row m's MFMA (compiler emits partial lgkmcnt waits) ----
      s16x8 af[8], bf[4];
#pragma unroll
      for (int nf = 0; nf < 4; ++nf)
        bf[nf] = *reinterpret_cast<const s16x8*>(
            Bbuf + ((wn * 64 + nf * 16 + r) << 5) + pg * 8);
      af[0] = *reinterpret_cast<const s16x8*>(
          Abuf + ((wm * 128 + 0 * 16 + r) << 5) + pg * 8);
      af[1] = *reinterpret_cast<const s16x8*>(
          Abuf + ((wm * 128 + 1 * 16 + r) << 5) + pg * 8);

      __builtin_amdgcn_s_setprio(1);
#pragma unroll
      for (int m = 0; m < 8; ++m) {
        if (m + 2 < 8)
          af[m + 2] = *reinterpret_cast<const s16x8*>(
              Abuf + ((wm * 128 + (m + 2) * 16 + r) << 5) + pg * 8);
#pragma unroll
        for (int nf = 0; nf < 4; ++nf)
          acc[m][nf] = MFMA_BF16(af[m], bf[nf], acc[m][nf]);
      }
      __builtin_amdgcn_s_setprio(0);

      asm volatile("s_waitcnt lgkmcnt(0)" ::: "memory");
      asm volatile("s_barrier" ::: "memory");
    }
  }
  asm volatile("s_waitcnt vmcnt(0)" ::: "memory");

  // ---- epilogue: C write (bf16) ----
#pragma unroll
  for (int m = 0; m < 8; ++m)
#pragma unroll
    for (int jj = 0; jj < 4; ++jj) {
      int crow = bm * 256 + wm * 128 + m * 16 + g * 4 + jj;
      size_t off = (size_t)crow * gn + bn * 256 + wn * 64 + r;
#pragma unroll
      for (int nf = 0; nf < 4; ++nf) C[off + nf * 16] = f2bf(acc[m][nf][jj]);
    }
}

// ---------------------------------------------------------------------------
// Final GEMM (ctx @ Wo^T), m97 structure, fp32 out, T1 swizzle (unchanged).
// ---------------------------------------------------------------------------
__global__ __launch_bounds__(256, 2)
void gemm_out(const short* __restrict__ A, const short* __restrict__ B,
              float* __restrict__ C) {
  __shared__ __align__(16) short As[128 * 64];
  __shared__ __align__(16) short Bs[128 * 64];
  const int d = blockIdx.x + (blockIdx.y << 4);
  const int tile = ((d & 7) << 6) | (d >> 3);
  const int bm = tile >> 4, bn = tile & 15;

  const int tid = threadIdx.x;
  const int lane = tid & 63;
  const int wid = tid >> 6;
  const int wr = wid >> 1, wc = wid & 1;
  const int g = lane >> 4, r = lane & 15;

  const f32x4 fz = {0.f, 0.f, 0.f, 0.f};
  f32x4 acc[4][4];
#pragma unroll
  for (int m = 0; m < 4; ++m)
#pragma unroll
    for (int n = 0; n < 4; ++n) acc[m][n] = fz;

  const short* Ab = A + (size_t)bm * 128 * GK;
  const short* Bb = B + (size_t)bn * 128 * GK;

  for (int kt = 0; kt < GK; kt += 64) {
#pragma unroll
    for (int i = 0; i < 4; ++i) {
      int c = i * 256 + tid;
      int row = c >> 3, c8 = c & 7;
      gload16(Ab + (size_t)row * GK + kt + c8 * 8, As + c * 8);
      gload16(Bb + (size_t)row * GK + kt + c8 * 8, Bs + c * 8);
    }
    __syncthreads();
#pragma unroll
    for (int kk = 0; kk < 2; ++kk) {
      s16x8 af[4], bf[4];
#pragma unroll
      for (int m = 0; m < 4; ++m)
        af[m] = *reinterpret_cast<const s16x8*>(As + (wr * 64 + m * 16 + r) * 64 + kk * 32 + g * 8);
#pragma unroll
      for (int n = 0; n < 4; ++n)
        bf[n] = *reinterpret_cast<const s16x8*>(Bs + (wc * 64 + n * 16 + r) * 64 + kk * 32 + g * 8);
#pragma unroll
      for (int m = 0; m < 4; ++m)
#pragma unroll
        for (int n = 0; n < 4; ++n) acc[m][n] = MFMA_BF16(af[m], bf[n], acc[m][n]);
    }
    __syncthreads();
  }

#pragma unroll
  for (int m = 0; m < 4; ++m)
#pragma unroll
    for (int jj = 0; jj < 4; ++jj) {
      int crow = bm * 128 + wr * 64 + m * 16 + g * 4 + jj;
      size_t off = (size_t)crow * 2048 + bn * 128 + wc * 64 + r;
#pragma unroll
      for (int n = 0; n < 4; ++n) C[off + n * 16] = acc[m][n][jj];
    }
}

// ---------------------------------------------------------------------------
// MFMA flash attention (r18, unchanged).
// ---------------------------------------------------------------------------
__global__ __launch_bounds__(256, 2)
void attn(const short* __restrict__ Q, const short* __restrict__ K,
          const short* __restrict__ VT, short* __restrict__ O) {
  __shared__ __align__(16) short Ks[64 * 136];
  __shared__ __align__(16) short Vt[128 * 72];
  __shared__ __align__(16) short Ps[4][2][16 * 72];

  const int tid = threadIdx.x;
  const int lane = tid & 63;
  const int wid = tid >> 6;
  const int g = lane >> 4, r = lane & 15;

  const int dflat = blockIdx.x + (blockIdx.y << 4);
  const int cflat = ((dflat & 7) << 6) + (dflat >> 3);
  const int qb = cflat & 15;
  const int bh = cflat >> 4;
  const int b = bh >> 4, h = bh & 15;
  const size_t base = (size_t)b * SL * EMB + (size_t)h * HD;
  const size_t vbase = (size_t)h * HD * 4096 + (size_t)b * SL;

  const int q0 = qb * 128 + wid * 32;
  s16x8 qf[2][4];
#pragma unroll
  for (int s = 0; s < 2; ++s)
#pragma unroll
    for (int kk = 0; kk < 4; ++kk)
      qf[s][kk] = *reinterpret_cast<const s16x8*>(
          Q + base + (size_t)(q0 + s * 16 + r) * EMB + kk * 32 + g * 8);

  const f32x4 fz = {0.f, 0.f, 0.f, 0.f};
  float l_run[2][4];
  f32x4 acc_o[2][8];
#pragma unroll
  for (int s = 0; s < 2; ++s) {
#pragma unroll
    for (int i = 0; i < 4; ++i) l_run[s][i] = 0.f;
#pragma unroll
    for (int i = 0; i < 8; ++i) acc_o[s][i] = fz;
  }

  const float SCALE = 0.08838834764831845f;
  const float C50I = 0.02f;
  const float CA = -1.f / 3.f, CB = 2.f / 15.f;

  const int rk = tid >> 4, ck = tid & 15;
  const int rv = tid >> 3, cv = tid & 7;
  const int cvx = cv ^ (rv & 7);
  s16x8 kreg[4], vreg[4];
#pragma unroll
  for (int i = 0; i < 4; ++i) {
    kreg[i] = *reinterpret_cast<const s16x8*>(K + base + (size_t)(rk + i * 16) * EMB + ck * 8);
    vreg[i] = *reinterpret_cast<const s16x8*>(VT + vbase + (size_t)(rv + i * 32) * 4096 + cv * 8);
  }

  for (int t = 0; t < SL / 64; ++t) {
    __syncthreads();
#pragma unroll
    for (int i = 0; i < 4; ++i) {
      *reinterpret_cast<s16x8*>(&Ks[(rk + i * 16) * 136 + ck * 8]) = kreg[i];
      *reinterpret_cast<s16x8*>(&Vt[(rv + i * 32) * 72 + (cvx << 3)]) = vreg[i];
    }
    __syncthreads();

    if (t + 1 < SL / 64) {
      const int kv1 = (t + 1) * 64;
#pragma unroll
      for (int i = 0; i < 4; ++i) {
        kreg[i] = *reinterpret_cast<const s16x8*>(K + base + (size_t)(kv1 + rk + i * 16) * EMB + ck * 8);
        vreg[i] = *reinterpret_cast<const s16x8*>(VT + vbase + (size_t)(rv + i * 32) * 4096 + kv1 + cv * 8);
      }
    }

    f32x4 sv[2][4];
    __builtin_amdgcn_s_setprio(1);
#pragma unroll
    for (int kn = 0; kn < 4; ++kn) {
      sv[0][kn] = fz; sv[1][kn] = fz;
#pragma unroll
      for (int kk = 0; kk < 4; ++kk) {
        s16x8 kf = *reinterpret_cast<const s16x8*>(&Ks[(kn * 16 + r) * 136 + kk * 32 + g * 8]);
        sv[0][kn] = MFMA_BF16(qf[0][kk], kf, sv[0][kn]);
        sv[1][kn] = MFMA_BF16(qf[1][kk], kf, sv[1][kn]);
      }
    }
    __builtin_amdgcn_s_setprio(0);

#pragma unroll
    for (int s = 0; s < 2; ++s)
#pragma unroll
      for (int kn = 0; kn < 4; ++kn)
#pragma unroll
        for (int reg = 0; reg < 4; ++reg) {
          float z = sv[s][kn][reg] * SCALE;
          float x = z * C50I;
          float x2 = x * x;
          float poly = __builtin_fmaf(x2, __builtin_fmaf(x2, CB, CA), 1.f);
          float cap = fminf(z * poly, 50.f);
          float pe = __expf(cap - 50.f);
          l_run[s][reg] += pe;
          sv[s][kn][reg] = pe;
        }

#pragma unroll
    for (int s = 0; s < 2; ++s)
#pragma unroll
      for (int kn = 0; kn < 4; ++kn)
#pragma unroll
        for (int reg = 0; reg < 4; ++reg)
          Ps[wid][s][(g * 4 + reg) * 72 + kn * 16 + r] = f2bf(sv[s][kn][reg]);

    __builtin_amdgcn_s_setprio(1);
#pragma unroll
    for (int c = 0; c < 2; ++c) {
      s16x8 pa0 = *reinterpret_cast<const s16x8*>(&Ps[wid][0][r * 72 + c * 32 + g * 8]);
      s16x8 pa1 = *reinterpret_cast<const s16x8*>(&Ps[wid][1][r * 72 + c * 32 + g * 8]);
#pragma unroll
      for (int dn = 0; dn < 8; ++dn) {
        int d = dn * 16 + r;
        int pc = ((c * 4 + g) ^ (r & 7));
        s16x8 vf = *reinterpret_cast<const s16x8*>(&Vt[d * 72 + (pc << 3)]);
        acc_o[0][dn] = MFMA_BF16(pa0, vf, acc_o[0][dn]);
        acc_o[1][dn] = MFMA_BF16(pa1, vf, acc_o[1][dn]);
      }
    }
    __builtin_amdgcn_s_setprio(0);
  }

#pragma unroll
  for (int s = 0; s < 2; ++s) {
#pragma unroll
    for (int reg = 0; reg < 4; ++reg) {
#pragma unroll
      for (int off = 1; off < 16; off <<= 1)
        l_run[s][reg] += __shfl_xor(l_run[s][reg], off);
      l_run[s][reg] = 1.f / l_run[s][reg];
    }
#pragma unroll
    for (int dn = 0; dn < 8; ++dn)
#pragma unroll
      for (int reg = 0; reg < 4; ++reg) {
        int row = q0 + s * 16 + g * 4 + reg;
        O[base + (size_t)row * EMB + dn * 16 + r] = f2bf(acc_o[s][dn][reg] * l_run[s][reg]);
      }
  }
}

__global__ void fill_f32(float* p, int n, float val) {
  int i = blockIdx.x * blockDim.x + threadIdx.x;
  if (i < n) p[i] = val;
}

// ---------------------------------------------------------------------------
extern "C" void kernel_launch(void* const* d_in, const int* in_sizes, int n_in,
                              void* d_out, int out_size, void* d_ws, size_t ws_size,
                              hipStream_t stream) {
  const float* q  = (const float*)d_in[0];
  const float* k  = (const float*)d_in[1];
  const float* v  = (const float*)d_in[2];
  const float* wq = (const float*)d_in[3];
  const float* wk = (const float*)d_in[4];
  const float* wv = (const float*)d_in[5];
  const float* wo = (const float*)d_in[6];
  float* out = (float*)d_out;

  bool ok = (n_in == 7) && out_size == 8388608;
  for (int i = 0; i < 3 && ok; ++i) ok = (in_sizes[i] == 8388608);
  for (int i = 3; i < 7 && ok; ++i) ok = (in_sizes[i] == 4194304);
  if (!ok) {
    fill_f32<<<(out_size + 255) / 256, 256, 0, stream>>>(out, out_size, 150.f);
    return;
  }

  const size_t NA = 8388608;
  const size_t NW = 4194304;
  const size_t need = (3 * NA + 4 * NW + 4 * NA) * sizeof(short); // 144 MiB
  if (ws_size < need) {
    fill_f32<<<(out_size + 255) / 256, 256, 0, stream>>>(out, out_size, 128.f);
    return;
  }

  short* bq  = (short*)d_ws;                 // cvt dst, contiguous
  short* bk  = bq + NA;
  short* bv  = bk + NA;
  short* bwq = bv + NA;
  short* bwk = bwq + NW;
  short* bwv = bwk + NW;
  short* bwo = bwv + NW;
  short* Qp  = bwo + NW;
  short* Kp  = Qp + NA;
  short* VpT = Kp + NA;                      // [2048 features][4096 tokens]
  short* Cx  = VpT + NA;

  dim3 g8(8, 16, 3);                         // 384 blocks x 512 threads
  dim3 gg(16, 32);                           // out GEMM (m97)
  dim3 ga(16, 32);                           // attn: 512 blocks

  cvt_all<<<2048, 256, 0, stream>>>(q, k, v, wq, wk, wv, wo, bq);
  gemm8_qkv<<<g8, dim3(512), 0, stream>>>(bq, bk, bwq, bwk, bwv, bv, Qp, Kp, VpT);
  attn<<<ga, dim3(256), 0, stream>>>(Qp, Kp, VpT, Cx);
  gemm_out<<<gg, dim3(256), 0, stream>>>(Cx, bwo, out);
}